// Round 6
// baseline (756.306 us; speedup 1.0000x reference)
//
#include <hip/hip_runtime.h>
#include <hip/hip_bf16.h>
#include <stdint.h>

typedef __hip_bfloat16 bf16;
typedef __attribute__((ext_vector_type(8))) short bf16x8;   // 8 bf16 = 4 VGPRs (MFMA A/B frag)
typedef __attribute__((ext_vector_type(4))) float f32x4;    // MFMA C/D frag

__device__ __forceinline__ float b2f(bf16 v) { return __bfloat162float(v); }
__device__ __forceinline__ bf16  f2b(float v) { return __float2bfloat16(v); }

// Input dtypes (established r0-r5): x/W/b/lw/lb = float32, masks = int32 (bool),
// output = float32. Internal pipeline: bf16 activations/weights, fp32 accum.
// Dims: D = {9229, 1387, 1066, 447, 147, 26}; K-pads {9248,1408,1088,448,160,32}

// ---------------------------------------------------------------------------
// Masked-transpose prep: Wt[n][k] = (k<K && n<N && mask[k][n]) ? W[k][n] : 0 (bf16)
__global__ void prep_wt(const float* __restrict__ W, const int* __restrict__ mask,
                        bf16* __restrict__ Wt, int K, int N, int Kpad) {
    __shared__ bf16 tile[32][33];
    int k0 = blockIdx.x * 32;
    int n0 = blockIdx.y * 32;
    int tx = threadIdx.x, ty = threadIdx.y;
    int k = k0 + ty, n = n0 + tx;
    float v = 0.f;
    if (k < K && n < N) {
        size_t idx = (size_t)k * N + n;
        if (mask[idx]) v = W[idx];
    }
    tile[ty][tx] = f2b(v);
    __syncthreads();
    Wt[(size_t)(n0 + ty) * Kpad + (k0 + tx)] = tile[tx][ty];
}

// Diagonal layer: act0[b][g] = tanh(sum_{j<3} x[b][3g+j]*w0[3g+j] + b0[g]); zero-pad to 9248.
__global__ void diag_tanh(const float* __restrict__ x, const float* __restrict__ w0,
                          const float* __restrict__ b0, bf16* __restrict__ out) {
    int g = blockIdx.x * 256 + threadIdx.x;
    int b = blockIdx.y;
    if (g >= 9248) return;
    float v = 0.f;
    if (g < 9229) {
        const float* xp = x + (size_t)b * 27687 + g * 3;
        const float* wp = w0 + g * 3;
        float s = xp[0] * wp[0] + xp[1] * wp[1] + xp[2] * wp[2];
        v = tanhf(s + b0[g]);
    }
    out[(size_t)b * 9248 + g] = f2b(v);
}

// Sigmoid head: out[b*6+idx] = sigmoid(dot(act[b,:D], lw) + lb), fp32 out.
__global__ void head_sig(const bf16* __restrict__ act, int ld, int D,
                         const float* __restrict__ lw, const float* __restrict__ lb,
                         float* __restrict__ out, int idx) {
    int b = blockIdx.x;
    const bf16* ap = act + (size_t)b * ld;
    float s = 0.f;
    for (int t = threadIdx.x; t < D; t += 256)
        s += b2f(ap[t]) * lw[t];
    #pragma unroll
    for (int off = 32; off > 0; off >>= 1) s += __shfl_down(s, off);
    __shared__ float red[4];
    if ((threadIdx.x & 63) == 0) red[threadIdx.x >> 6] = s;
    __syncthreads();
    if (threadIdx.x == 0) {
        float t = red[0] + red[1] + red[2] + red[3] + lb[0];
        out[b * 6 + idx] = 1.f / (1.f + expf(-t));
    }
}

// Head 1 without materialized act0 (tier B): recompute diag on the fly.
__global__ void head1_diag(const float* __restrict__ x, const float* __restrict__ w0,
                           const float* __restrict__ b0, const float* __restrict__ lw,
                           const float* __restrict__ lb, float* __restrict__ out) {
    int b = blockIdx.x;
    const float* xr = x + (size_t)b * 27687;
    float s = 0.f;
    for (int g = threadIdx.x; g < 9229; g += 256) {
        int p = 3 * g;
        float a = tanhf(xr[p] * w0[p] + xr[p+1] * w0[p+1] + xr[p+2] * w0[p+2] + b0[g]);
        s += f2b(a) == f2b(a) ? b2f(f2b(a)) * lw[g] : 0.f;  // match bf16-act rounding
    }
    #pragma unroll
    for (int off = 32; off > 0; off >>= 1) s += __shfl_down(s, off);
    __shared__ float red[4];
    if ((threadIdx.x & 63) == 0) red[threadIdx.x >> 6] = s;
    __syncthreads();
    if (threadIdx.x == 0) {
        float t = red[0] + red[1] + red[2] + red[3] + lb[0];
        out[b * 6] = 1.f / (1.f + expf(-t));
    }
}

// ---------------------------------------------------------------------------
// GEMM kernels (128x128 tile, BK=32, 2x2 waves, 4x4 16x16x32 bf16 MFMA)
// ---------------------------------------------------------------------------

__global__ __launch_bounds__(256) void gemm_bt_tanh(
        const bf16* __restrict__ A, const bf16* __restrict__ Bt,
        const float* __restrict__ bias, bf16* __restrict__ C,
        int lda, int N, int Npad, int ldc, int kIters) {
    __shared__ uint4 As[512];
    __shared__ uint4 Bs[512];

    int tid  = threadIdx.x;
    int wave = tid >> 6;
    int lane = tid & 63;
    int m16  = lane & 15;
    int quad = lane >> 4;
    int wr = (wave >> 1) * 64;
    int wc = (wave & 1) * 64;
    int bm = blockIdx.y * 128;
    int bn = blockIdx.x * 128;
    int r0 = tid >> 2;
    int c0 = (tid & 3) * 8;

    const bf16* Abase = A  + (size_t)bm * lda;
    const bf16* Bbase = Bt + (size_t)bn * lda;

    f32x4 acc[4][4];
    #pragma unroll
    for (int i = 0; i < 4; i++)
        #pragma unroll
        for (int j = 0; j < 4; j++)
            acc[i][j] = (f32x4){0.f, 0.f, 0.f, 0.f};

    for (int kt = 0; kt < kIters; ++kt) {
        int k0 = kt * 32;
        uint4 a0 = *(const uint4*)(Abase + (size_t)r0 * lda + k0 + c0);
        uint4 a1 = *(const uint4*)(Abase + (size_t)(r0 + 64) * lda + k0 + c0);
        uint4 b0 = *(const uint4*)(Bbase + (size_t)r0 * lda + k0 + c0);
        uint4 b1 = *(const uint4*)(Bbase + (size_t)(r0 + 64) * lda + k0 + c0);
        __syncthreads();
        As[tid]       = a0;
        As[tid + 256] = a1;
        Bs[tid]       = b0;
        Bs[tid + 256] = b1;
        __syncthreads();

        bf16x8 af[4], bfr[4];
        #pragma unroll
        for (int i = 0; i < 4; i++)
            af[i] = *(const bf16x8*)&As[(wr + i * 16 + m16) * 4 + quad];
        #pragma unroll
        for (int j = 0; j < 4; j++)
            bfr[j] = *(const bf16x8*)&Bs[(wc + j * 16 + m16) * 4 + quad];

        #pragma unroll
        for (int i = 0; i < 4; i++)
            #pragma unroll
            for (int j = 0; j < 4; j++)
                acc[i][j] = __builtin_amdgcn_mfma_f32_16x16x32_bf16(af[i], bfr[j], acc[i][j], 0, 0, 0);
    }

    #pragma unroll
    for (int i = 0; i < 4; i++)
        #pragma unroll
        for (int j = 0; j < 4; j++) {
            int col = bn + wc + j * 16 + m16;
            if (col < Npad) {
                bool real = col < N;
                float bv = real ? bias[col] : 0.f;
                #pragma unroll
                for (int r = 0; r < 4; r++) {
                    int m = bm + wr + i * 16 + quad * 4 + r;
                    float o = real ? tanhf(acc[i][j][r] + bv) : 0.f;
                    C[(size_t)m * ldc + col] = f2b(o);
                }
            }
        }
}

// B = (W ⊙ mask) staged on the fly from row-major fp32 [K,N] + int32 mask.
__global__ __launch_bounds__(256) void gemm_fused_mask_tanh(
        const bf16* __restrict__ A, const float* __restrict__ W,
        const int* __restrict__ mask, const float* __restrict__ bias,
        bf16* __restrict__ C,
        int lda, int K, int N, int Npad, int ldc, int kIters) {
    __shared__ uint4 As[512];
    __shared__ bf16  Bsh[128 * 32];

    int tid  = threadIdx.x;
    int wave = tid >> 6;
    int lane = tid & 63;
    int m16  = lane & 15;
    int quad = lane >> 4;
    int wr = (wave >> 1) * 64;
    int wc = (wave & 1) * 64;
    int bm = blockIdx.y * 128;
    int bn = blockIdx.x * 128;
    int r0 = tid >> 2;
    int c0 = (tid & 3) * 8;
    int bk  = tid >> 3;
    int bn0 = (tid & 7) * 16;

    const bf16* Abase = A + (size_t)bm * lda;

    f32x4 acc[4][4];
    #pragma unroll
    for (int i = 0; i < 4; i++)
        #pragma unroll
        for (int j = 0; j < 4; j++)
            acc[i][j] = (f32x4){0.f, 0.f, 0.f, 0.f};

    for (int kt = 0; kt < kIters; ++kt) {
        int k0 = kt * 32;
        uint4 a0 = *(const uint4*)(Abase + (size_t)r0 * lda + k0 + c0);
        uint4 a1 = *(const uint4*)(Abase + (size_t)(r0 + 64) * lda + k0 + c0);
        int gk = k0 + bk;
        bool krow = gk < K;
        const float* wrow = W    + (size_t)gk * N;
        const int*   mrow = mask + (size_t)gk * N;
        __syncthreads();
        As[tid]       = a0;
        As[tid + 256] = a1;
        #pragma unroll
        for (int j = 0; j < 16; j++) {
            int n = bn + bn0 + j;
            float v = 0.f;
            if (krow && n < N && mrow[n]) v = wrow[n];
            Bsh[(bn0 + j) * 32 + bk] = f2b(v);
        }
        __syncthreads();

        bf16x8 af[4], bfr[4];
        #pragma unroll
        for (int i = 0; i < 4; i++)
            af[i] = *(const bf16x8*)&As[(wr + i * 16 + m16) * 4 + quad];
        #pragma unroll
        for (int j = 0; j < 4; j++)
            bfr[j] = *(const bf16x8*)&Bsh[(wc + j * 16 + m16) * 32 + quad * 8];

        #pragma unroll
        for (int i = 0; i < 4; i++)
            #pragma unroll
            for (int j = 0; j < 4; j++)
                acc[i][j] = __builtin_amdgcn_mfma_f32_16x16x32_bf16(af[i], bfr[j], acc[i][j], 0, 0, 0);
    }

    #pragma unroll
    for (int i = 0; i < 4; i++)
        #pragma unroll
        for (int j = 0; j < 4; j++) {
            int col = bn + wc + j * 16 + m16;
            if (col < Npad) {
                bool real = col < N;
                float bv = real ? bias[col] : 0.f;
                #pragma unroll
                for (int r = 0; r < 4; r++) {
                    int m = bm + wr + i * 16 + quad * 4 + r;
                    float o = real ? tanhf(acc[i][j][r] + bv) : 0.f;
                    C[(size_t)m * ldc + col] = f2b(o);
                }
            }
        }
}

// Tier-B layer-1 GEMM: diag layer (A from fp32 x) AND mask⊙W both fused. Fixed dims.
__global__ __launch_bounds__(256) void gemm1_diag_fused(
        const float* __restrict__ x, const float* __restrict__ w0, const float* __restrict__ b0g,
        const float* __restrict__ W, const int* __restrict__ mask,
        const float* __restrict__ bias, bf16* __restrict__ C) {
    __shared__ bf16 Ash[128 * 32];
    __shared__ bf16 Bsh[128 * 32];

    int tid  = threadIdx.x;
    int wave = tid >> 6;
    int lane = tid & 63;
    int m16  = lane & 15;
    int quad = lane >> 4;
    int wr = (wave >> 1) * 64;
    int wc = (wave & 1) * 64;
    int bm = blockIdx.y * 128;
    int bn = blockIdx.x * 128;
    int ar  = tid >> 1;
    int ak0 = (tid & 1) * 16;
    int bk  = tid >> 3;
    int bn0 = (tid & 7) * 16;

    const float* xrow = x + (size_t)(bm + ar) * 27687;

    f32x4 acc[4][4];
    #pragma unroll
    for (int i = 0; i < 4; i++)
        #pragma unroll
        for (int j = 0; j < 4; j++)
            acc[i][j] = (f32x4){0.f, 0.f, 0.f, 0.f};

    for (int kt = 0; kt < 289; ++kt) {
        int k0 = kt * 32;
        __syncthreads();
        #pragma unroll
        for (int t = 0; t < 16; t++) {
            int g = k0 + ak0 + t;
            float v = 0.f;
            if (g < 9229) {
                int p = 3 * g;
                v = tanhf(xrow[p] * w0[p] + xrow[p+1] * w0[p+1] + xrow[p+2] * w0[p+2] + b0g[g]);
            }
            Ash[ar * 32 + ak0 + t] = f2b(v);
        }
        {
            int gk = k0 + bk;
            bool krow = gk < 9229;
            const float* wrow = W    + (size_t)gk * 1387;
            const int*   mrow = mask + (size_t)gk * 1387;
            #pragma unroll
            for (int j = 0; j < 16; j++) {
                int n = bn + bn0 + j;
                float v = 0.f;
                if (krow && n < 1387 && mrow[n]) v = wrow[n];
                Bsh[(bn0 + j) * 32 + bk] = f2b(v);
            }
        }
        __syncthreads();

        bf16x8 af[4], bfr[4];
        #pragma unroll
        for (int i = 0; i < 4; i++)
            af[i] = *(const bf16x8*)&Ash[(wr + i * 16 + m16) * 32 + quad * 8];
        #pragma unroll
        for (int j = 0; j < 4; j++)
            bfr[j] = *(const bf16x8*)&Bsh[(wc + j * 16 + m16) * 32 + quad * 8];

        #pragma unroll
        for (int i = 0; i < 4; i++)
            #pragma unroll
            for (int j = 0; j < 4; j++)
                acc[i][j] = __builtin_amdgcn_mfma_f32_16x16x32_bf16(af[i], bfr[j], acc[i][j], 0, 0, 0);
    }

    #pragma unroll
    for (int i = 0; i < 4; i++)
        #pragma unroll
        for (int j = 0; j < 4; j++) {
            int col = bn + wc + j * 16 + m16;
            if (col < 1408) {
                bool real = col < 1387;
                float bv = real ? bias[col] : 0.f;
                #pragma unroll
                for (int r = 0; r < 4; r++) {
                    int m = bm + wr + i * 16 + quad * 4 + r;
                    float o = real ? tanhf(acc[i][j][r] + bv) : 0.f;
                    C[(size_t)m * 1408 + col] = f2b(o);
                }
            }
        }
}

// ---------------------------------------------------------------------------
// Zero-workspace fallback: one block per batch row, activations in LDS.
// ---------------------------------------------------------------------------
__device__ __forceinline__ void head_dev(const bf16* a, int D, const float* lw,
                                         const float* lb, float* out, int oidx,
                                         float* red, int tid) {
    float s = 0.f;
    for (int t = tid; t < D; t += 256) s += b2f(a[t]) * lw[t];
    #pragma unroll
    for (int off = 32; off > 0; off >>= 1) s += __shfl_down(s, off);
    __syncthreads();
    if ((tid & 63) == 0) red[tid >> 6] = s;
    __syncthreads();
    if (tid == 0) {
        float t = red[0] + red[1] + red[2] + red[3] + lb[0];
        out[oidx] = 1.f / (1.f + expf(-t));
    }
}

__device__ __forceinline__ void layer_dev(const bf16* ain, int K, int N,
                                          const float* W, const int* m,
                                          const float* bias, bf16* aout, int Npad, int tid) {
    __syncthreads();
    for (int n = tid; n < Npad; n += 256) {
        float v = 0.f;
        if (n < N) {
            float s = 0.f;
            for (int k = 0; k < K; k++) {
                size_t idx = (size_t)k * N + n;
                if (m[idx]) s += b2f(ain[k]) * W[idx];
            }
            v = tanhf(s + bias[n]);
        }
        aout[n] = f2b(v);
    }
    __syncthreads();
}

__global__ __launch_bounds__(256) void forward_monolithic(
        const float* __restrict__ x, const float* __restrict__ w0, const float* __restrict__ b0,
        const float* W1, const float* bb1, const int* m1,
        const float* W2, const float* bb2, const int* m2,
        const float* W3, const float* bb3, const int* m3,
        const float* W4, const float* bb4, const int* m4,
        const float* W5, const float* bb5, const int* m5,
        const float* l1w, const float* l1b, const float* l2w, const float* l2b,
        const float* l3w, const float* l3b, const float* l4w, const float* l4b,
        const float* l5w, const float* l5b, const float* l6w, const float* l6b,
        float* __restrict__ out) {
    __shared__ bf16 A0[9232];
    __shared__ bf16 A1[1392];
    __shared__ bf16 A2[1072];
    __shared__ bf16 A3[448];
    __shared__ bf16 A4[160];
    __shared__ bf16 A5[32];
    __shared__ float red[4];
    int b = blockIdx.x, tid = threadIdx.x;
    const float* xr = x + (size_t)b * 27687;
    for (int g = tid; g < 9232; g += 256) {
        float v = 0.f;
        if (g < 9229) {
            int p = 3 * g;
            v = tanhf(xr[p] * w0[p] + xr[p+1] * w0[p+1] + xr[p+2] * w0[p+2] + b0[g]);
        }
        A0[g] = f2b(v);
    }
    __syncthreads();
    int ob = b * 6;
    head_dev(A0, 9229, l1w, l1b, out, ob + 0, red, tid);
    layer_dev(A0, 9229, 1387, W1, m1, bb1, A1, 1392, tid);
    head_dev(A1, 1387, l2w, l2b, out, ob + 1, red, tid);
    layer_dev(A1, 1387, 1066, W2, m2, bb2, A2, 1072, tid);
    head_dev(A2, 1066, l3w, l3b, out, ob + 2, red, tid);
    layer_dev(A2, 1066, 447, W3, m3, bb3, A3, 448, tid);
    head_dev(A3, 447, l4w, l4b, out, ob + 3, red, tid);
    layer_dev(A3, 447, 147, W4, m4, bb4, A4, 160, tid);
    head_dev(A4, 147, l5w, l5b, out, ob + 4, red, tid);
    layer_dev(A4, 147, 26, W5, m5, bb5, A5, 32, tid);
    head_dev(A5, 26, l6w, l6b, out, ob + 5, red, tid);
}

// ---------------------------------------------------------------------------

extern "C" void kernel_launch(void* const* d_in, const int* in_sizes, int n_in,
                              void* d_out, int out_size, void* d_ws, size_t ws_size,
                              hipStream_t stream) {
    const float* x  = (const float*)d_in[0];
    const float* w0 = (const float*)d_in[1];
    const float* b0 = (const float*)d_in[2];
    const float* W[5]  = {(const float*)d_in[3], (const float*)d_in[6], (const float*)d_in[9],
                          (const float*)d_in[12], (const float*)d_in[15]};
    const float* bb[5] = {(const float*)d_in[4], (const float*)d_in[7], (const float*)d_in[10],
                          (const float*)d_in[13], (const float*)d_in[16]};
    const int* mk[5] = {(const int*)d_in[5], (const int*)d_in[8], (const int*)d_in[11],
                        (const int*)d_in[14], (const int*)d_in[17]};
    const float* lw[6] = {(const float*)d_in[18], (const float*)d_in[20], (const float*)d_in[22],
                          (const float*)d_in[24], (const float*)d_in[26], (const float*)d_in[28]};
    const float* lb[6] = {(const float*)d_in[19], (const float*)d_in[21], (const float*)d_in[23],
                          (const float*)d_in[25], (const float*)d_in[27], (const float*)d_in[29]};
    float* out = (float*)d_out;
    char* ws = (char*)d_ws;
    dim3 b32(32, 32);

    if (ws_size >= 56033280) {
        // FULL
        bf16* act0 = (bf16*)(ws + 0);
        bf16* act1 = (bf16*)(ws + 18939904);
        bf16* act2 = (bf16*)(ws + 21823488);
        bf16* act3 = (bf16*)(ws + 24051712);
        bf16* act4 = (bf16*)(ws + 24969216);
        bf16* act5 = (bf16*)(ws + 25296896);
        bf16* wt1  = (bf16*)(ws + 25362432);
        bf16* wt2  = (bf16*)(ws + 51404800);
        bf16* wt3  = (bf16*)(ws + 54648832);
        bf16* wt4  = (bf16*)(ws + 55762944);
        bf16* wt5  = (bf16*)(ws + 55992320);

        diag_tanh<<<dim3(37, 1024), 256, 0, stream>>>(x, w0, b0, act0);
        head_sig<<<1024, 256, 0, stream>>>(act0, 9248, 9229, lw[0], lb[0], out, 0);
        prep_wt<<<dim3(289, 44), b32, 0, stream>>>(W[0], mk[0], wt1, 9229, 1387, 9248);
        prep_wt<<<dim3(44, 36),  b32, 0, stream>>>(W[1], mk[1], wt2, 1387, 1066, 1408);
        prep_wt<<<dim3(34, 16),  b32, 0, stream>>>(W[2], mk[2], wt3, 1066, 447,  1088);
        prep_wt<<<dim3(14, 8),   b32, 0, stream>>>(W[3], mk[3], wt4, 447,  147,  448);
        prep_wt<<<dim3(5, 4),    b32, 0, stream>>>(W[4], mk[4], wt5, 147,  26,   160);
        gemm_bt_tanh<<<dim3(11, 8), 256, 0, stream>>>(act0, wt1, bb[0], act1, 9248, 1387, 1408, 1408, 289);
        head_sig<<<1024, 256, 0, stream>>>(act1, 1408, 1387, lw[1], lb[1], out, 1);
        gemm_bt_tanh<<<dim3(9, 8), 256, 0, stream>>>(act1, wt2, bb[1], act2, 1408, 1066, 1088, 1088, 44);
        head_sig<<<1024, 256, 0, stream>>>(act2, 1088, 1066, lw[2], lb[2], out, 2);
        gemm_bt_tanh<<<dim3(4, 8), 256, 0, stream>>>(act2, wt3, bb[2], act3, 1088, 447, 448, 448, 34);
        head_sig<<<1024, 256, 0, stream>>>(act3, 448, 447, lw[3], lb[3], out, 3);
        gemm_bt_tanh<<<dim3(2, 8), 256, 0, stream>>>(act3, wt4, bb[3], act4, 448, 147, 160, 160, 14);
        head_sig<<<1024, 256, 0, stream>>>(act4, 160, 147, lw[4], lb[4], out, 4);
        gemm_bt_tanh<<<dim3(1, 8), 256, 0, stream>>>(act4, wt5, bb[4], act5, 160, 26, 32, 32, 5);
        head_sig<<<1024, 256, 0, stream>>>(act5, 32, 26, lw[5], lb[5], out, 5);
    } else if (ws_size >= 28606464) {
        // COMPACT: act0 + acts + one shared wt slot; gemm1 fuses the mask.
        bf16* act0 = (bf16*)(ws + 0);
        bf16* act1 = (bf16*)(ws + 18939904);
        bf16* act2 = (bf16*)(ws + 21823488);
        bf16* act3 = (bf16*)(ws + 24051712);
        bf16* act4 = (bf16*)(ws + 24969216);
        bf16* act5 = (bf16*)(ws + 25296896);
        bf16* wtS  = (bf16*)(ws + 25362432);  // 3,244,032 B

        diag_tanh<<<dim3(37, 1024), 256, 0, stream>>>(x, w0, b0, act0);
        head_sig<<<1024, 256, 0, stream>>>(act0, 9248, 9229, lw[0], lb[0], out, 0);
        gemm_fused_mask_tanh<<<dim3(11, 8), 256, 0, stream>>>(act0, W[0], mk[0], bb[0], act1,
                                                              9248, 9229, 1387, 1408, 1408, 289);
        head_sig<<<1024, 256, 0, stream>>>(act1, 1408, 1387, lw[1], lb[1], out, 1);
        prep_wt<<<dim3(44, 36), b32, 0, stream>>>(W[1], mk[1], wtS, 1387, 1066, 1408);
        gemm_bt_tanh<<<dim3(9, 8), 256, 0, stream>>>(act1, wtS, bb[1], act2, 1408, 1066, 1088, 1088, 44);
        head_sig<<<1024, 256, 0, stream>>>(act2, 1088, 1066, lw[2], lb[2], out, 2);
        prep_wt<<<dim3(34, 16), b32, 0, stream>>>(W[2], mk[2], wtS, 1066, 447, 1088);
        gemm_bt_tanh<<<dim3(4, 8), 256, 0, stream>>>(act2, wtS, bb[2], act3, 1088, 447, 448, 448, 34);
        head_sig<<<1024, 256, 0, stream>>>(act3, 448, 447, lw[3], lb[3], out, 3);
        prep_wt<<<dim3(14, 8), b32, 0, stream>>>(W[3], mk[3], wtS, 447, 147, 448);
        gemm_bt_tanh<<<dim3(2, 8), 256, 0, stream>>>(act3, wtS, bb[3], act4, 448, 147, 160, 160, 14);
        head_sig<<<1024, 256, 0, stream>>>(act4, 160, 147, lw[4], lb[4], out, 4);
        prep_wt<<<dim3(5, 4), b32, 0, stream>>>(W[4], mk[4], wtS, 147, 26, 160);
        gemm_bt_tanh<<<dim3(1, 8), 256, 0, stream>>>(act4, wtS, bb[4], act5, 160, 26, 32, 32, 5);
        head_sig<<<1024, 256, 0, stream>>>(act5, 32, 26, lw[5], lb[5], out, 5);
    } else if (ws_size >= 6422528) {
        // TIER B: act1..act5 only (6.42 MB); diag + masks fused into GEMMs.
        bf16* act1 = (bf16*)(ws + 0);
        bf16* act2 = (bf16*)(ws + 2883584);
        bf16* act3 = (bf16*)(ws + 5111808);
        bf16* act4 = (bf16*)(ws + 6029312);
        bf16* act5 = (bf16*)(ws + 6356992);

        head1_diag<<<1024, 256, 0, stream>>>(x, w0, b0, lw[0], lb[0], out);
        gemm1_diag_fused<<<dim3(11, 8), 256, 0, stream>>>(x, w0, b0, W[0], mk[0], bb[0], act1);
        head_sig<<<1024, 256, 0, stream>>>(act1, 1408, 1387, lw[1], lb[1], out, 1);
        gemm_fused_mask_tanh<<<dim3(9, 8), 256, 0, stream>>>(act1, W[1], mk[1], bb[1], act2,
                                                             1408, 1387, 1066, 1088, 1088, 44);
        head_sig<<<1024, 256, 0, stream>>>(act2, 1088, 1066, lw[2], lb[2], out, 2);
        gemm_fused_mask_tanh<<<dim3(4, 8), 256, 0, stream>>>(act2, W[2], mk[2], bb[2], act3,
                                                             1088, 1066, 447, 448, 448, 34);
        head_sig<<<1024, 256, 0, stream>>>(act3, 448, 447, lw[3], lb[3], out, 3);
        gemm_fused_mask_tanh<<<dim3(2, 8), 256, 0, stream>>>(act3, W[3], mk[3], bb[3], act4,
                                                             448, 447, 147, 160, 160, 14);
        head_sig<<<1024, 256, 0, stream>>>(act4, 160, 147, lw[4], lb[4], out, 4);
        gemm_fused_mask_tanh<<<dim3(1, 8), 256, 0, stream>>>(act4, W[4], mk[4], bb[4], act5,
                                                             160, 147, 26, 32, 32, 5);
        head_sig<<<1024, 256, 0, stream>>>(act5, 32, 26, lw[5], lb[5], out, 5);
    } else {
        forward_monolithic<<<1024, 256, 0, stream>>>(
            x, w0, b0,
            W[0], bb[0], mk[0], W[1], bb[1], mk[1], W[2], bb[2], mk[2],
            W[3], bb[3], mk[3], W[4], bb[4], mk[4],
            lw[0], lb[0], lw[1], lb[1], lw[2], lb[2],
            lw[3], lb[3], lw[4], lb[4], lw[5], lb[5], out);
    }
}

// Round 7
// 571.596 us; speedup vs baseline: 1.3231x; 1.3231x over previous
//
#include <hip/hip_runtime.h>
#include <hip/hip_bf16.h>
#include <stdint.h>

typedef __hip_bfloat16 bf16;
typedef __attribute__((ext_vector_type(8))) short bf16x8;   // 8 bf16 = 4 VGPRs (MFMA A/B frag)
typedef __attribute__((ext_vector_type(4))) float f32x4;    // MFMA C/D frag

__device__ __forceinline__ float b2f(bf16 v) { return __bfloat162float(v); }
__device__ __forceinline__ bf16  f2b(float v) { return __float2bfloat16(v); }

// Input dtypes (established r0-r6): x/W/b/lw/lb = float32, masks = int32 (bool),
// output = float32. Internal: bf16 activations/weights, fp32 accum.
// Dims: D = {9229, 1387, 1066, 447, 147, 26}; K-pads {9248,1408,1088,448,160,32}

// ---------------------------------------------------------------------------
// Masked-transpose prep: Wt[n][k] = (k<K && n<N && mask[k][n]) ? W[k][n] : 0 (bf16)
__global__ void prep_wt(const float* __restrict__ W, const int* __restrict__ mask,
                        bf16* __restrict__ Wt, int K, int N, int Kpad) {
    __shared__ bf16 tile[32][33];
    int k0 = blockIdx.x * 32;
    int n0 = blockIdx.y * 32;
    int tx = threadIdx.x, ty = threadIdx.y;
    int k = k0 + ty, n = n0 + tx;
    float v = 0.f;
    if (k < K && n < N) {
        size_t idx = (size_t)k * N + n;
        if (mask[idx]) v = W[idx];
    }
    tile[ty][tx] = f2b(v);
    __syncthreads();
    Wt[(size_t)(n0 + ty) * Kpad + (k0 + tx)] = tile[tx][ty];
}

// Diagonal layer: act0[b][g] = tanh(sum_{j<3} x[b][3g+j]*w0[3g+j] + b0[g]); zero-pad to 9248.
__global__ void diag_tanh(const float* __restrict__ x, const float* __restrict__ w0,
                          const float* __restrict__ b0, bf16* __restrict__ out) {
    int g = blockIdx.x * 256 + threadIdx.x;
    int b = blockIdx.y;
    if (g >= 9248) return;
    float v = 0.f;
    if (g < 9229) {
        const float* xp = x + (size_t)b * 27687 + g * 3;
        const float* wp = w0 + g * 3;
        float s = xp[0] * wp[0] + xp[1] * wp[1] + xp[2] * wp[2];
        v = tanhf(s + b0[g]);
    }
    out[(size_t)b * 9248 + g] = f2b(v);
}

// Sigmoid head: out[b*6+idx] = sigmoid(dot(act[b,:D], lw) + lb), fp32 out.
__global__ void head_sig(const bf16* __restrict__ act, int ld, int D,
                         const float* __restrict__ lw, const float* __restrict__ lb,
                         float* __restrict__ out, int idx) {
    int b = blockIdx.x;
    const bf16* ap = act + (size_t)b * ld;
    float s = 0.f;
    for (int t = threadIdx.x; t < D; t += 256)
        s += b2f(ap[t]) * lw[t];
    #pragma unroll
    for (int off = 32; off > 0; off >>= 1) s += __shfl_down(s, off);
    __shared__ float red[4];
    if ((threadIdx.x & 63) == 0) red[threadIdx.x >> 6] = s;
    __syncthreads();
    if (threadIdx.x == 0) {
        float t = red[0] + red[1] + red[2] + red[3] + lb[0];
        out[b * 6 + idx] = 1.f / (1.f + expf(-t));
    }
}

// Zero an fp32 buffer (float4 stores). n4 = element count / 4.
__global__ void zero_f32(float* __restrict__ p, int n4) {
    int i = blockIdx.x * 256 + threadIdx.x;
    if (i < n4) ((float4*)p)[i] = make_float4(0.f, 0.f, 0.f, 0.f);
}

// Finalize split-K: act[m][n] = n<N ? tanh(C32[m][n] + bias[n]) : 0   (n < Npad=ld)
__global__ void finalize_tanh(const float* __restrict__ C32, const float* __restrict__ bias,
                              bf16* __restrict__ act, int ld, int N) {
    int n = blockIdx.x * 256 + threadIdx.x;
    int m = blockIdx.y;
    if (n >= ld) return;
    float v = 0.f;
    if (n < N) v = tanhf(C32[(size_t)m * ld + n] + bias[n]);
    act[(size_t)m * ld + n] = f2b(v);
}

// ---------------------------------------------------------------------------
// Split-K GEMM (bt form): C32[m][n] += sum_{k in split} A[m][k]*Bt[n][k]  (fp32 atomics)
// 256 threads (2x2 waves), tile 128x128, BK=32, 4x4 16x16x32 bf16 MFMA.
// Grid: (Ntiles, Mtiles, S). Split z covers k-iters [z*chunk, min(kIters,(z+1)*chunk)).
// ---------------------------------------------------------------------------
__global__ __launch_bounds__(256) void gemm_bt_splitk(
        const bf16* __restrict__ A, const bf16* __restrict__ Bt,
        float* __restrict__ C32,
        int lda, int ldc32, int Nguard, int kIters, int chunk) {
    __shared__ uint4 As[512];
    __shared__ uint4 Bs[512];

    int tid  = threadIdx.x;
    int wave = tid >> 6;
    int lane = tid & 63;
    int m16  = lane & 15;
    int quad = lane >> 4;
    int wr = (wave >> 1) * 64;
    int wc = (wave & 1) * 64;
    int bm = blockIdx.y * 128;
    int bn = blockIdx.x * 128;
    int r0 = tid >> 2;
    int c0 = (tid & 3) * 8;

    const bf16* Abase = A  + (size_t)bm * lda;
    const bf16* Bbase = Bt + (size_t)bn * lda;

    f32x4 acc[4][4];
    #pragma unroll
    for (int i = 0; i < 4; i++)
        #pragma unroll
        for (int j = 0; j < 4; j++)
            acc[i][j] = (f32x4){0.f, 0.f, 0.f, 0.f};

    int kStart = blockIdx.z * chunk;
    int kEnd = kStart + chunk;
    if (kEnd > kIters) kEnd = kIters;

    for (int kt = kStart; kt < kEnd; ++kt) {
        int k0 = kt * 32;
        uint4 a0 = *(const uint4*)(Abase + (size_t)r0 * lda + k0 + c0);
        uint4 a1 = *(const uint4*)(Abase + (size_t)(r0 + 64) * lda + k0 + c0);
        uint4 b0 = *(const uint4*)(Bbase + (size_t)r0 * lda + k0 + c0);
        uint4 b1 = *(const uint4*)(Bbase + (size_t)(r0 + 64) * lda + k0 + c0);
        __syncthreads();
        As[tid]       = a0;
        As[tid + 256] = a1;
        Bs[tid]       = b0;
        Bs[tid + 256] = b1;
        __syncthreads();

        bf16x8 af[4], bfr[4];
        #pragma unroll
        for (int i = 0; i < 4; i++)
            af[i] = *(const bf16x8*)&As[(wr + i * 16 + m16) * 4 + quad];
        #pragma unroll
        for (int j = 0; j < 4; j++)
            bfr[j] = *(const bf16x8*)&Bs[(wc + j * 16 + m16) * 4 + quad];

        #pragma unroll
        for (int i = 0; i < 4; i++)
            #pragma unroll
            for (int j = 0; j < 4; j++)
                acc[i][j] = __builtin_amdgcn_mfma_f32_16x16x32_bf16(af[i], bfr[j], acc[i][j], 0, 0, 0);
    }

    #pragma unroll
    for (int i = 0; i < 4; i++)
        #pragma unroll
        for (int j = 0; j < 4; j++) {
            int col = bn + wc + j * 16 + m16;
            if (col < Nguard) {
                #pragma unroll
                for (int r = 0; r < 4; r++) {
                    int m = bm + wr + i * 16 + quad * 4 + r;
                    unsafeAtomicAdd(&C32[(size_t)m * ldc32 + col], acc[i][j][r]);
                }
            }
        }
}

// Fused-epilogue GEMM for the small tail layers (4, 5).
__global__ __launch_bounds__(256) void gemm_bt_tanh(
        const bf16* __restrict__ A, const bf16* __restrict__ Bt,
        const float* __restrict__ bias, bf16* __restrict__ C,
        int lda, int N, int Npad, int ldc, int kIters) {
    __shared__ uint4 As[512];
    __shared__ uint4 Bs[512];

    int tid  = threadIdx.x;
    int wave = tid >> 6;
    int lane = tid & 63;
    int m16  = lane & 15;
    int quad = lane >> 4;
    int wr = (wave >> 1) * 64;
    int wc = (wave & 1) * 64;
    int bm = blockIdx.y * 128;
    int bn = blockIdx.x * 128;
    int r0 = tid >> 2;
    int c0 = (tid & 3) * 8;

    const bf16* Abase = A  + (size_t)bm * lda;
    const bf16* Bbase = Bt + (size_t)bn * lda;

    f32x4 acc[4][4];
    #pragma unroll
    for (int i = 0; i < 4; i++)
        #pragma unroll
        for (int j = 0; j < 4; j++)
            acc[i][j] = (f32x4){0.f, 0.f, 0.f, 0.f};

    for (int kt = 0; kt < kIters; ++kt) {
        int k0 = kt * 32;
        uint4 a0 = *(const uint4*)(Abase + (size_t)r0 * lda + k0 + c0);
        uint4 a1 = *(const uint4*)(Abase + (size_t)(r0 + 64) * lda + k0 + c0);
        uint4 b0 = *(const uint4*)(Bbase + (size_t)r0 * lda + k0 + c0);
        uint4 b1 = *(const uint4*)(Bbase + (size_t)(r0 + 64) * lda + k0 + c0);
        __syncthreads();
        As[tid]       = a0;
        As[tid + 256] = a1;
        Bs[tid]       = b0;
        Bs[tid + 256] = b1;
        __syncthreads();

        bf16x8 af[4], bfr[4];
        #pragma unroll
        for (int i = 0; i < 4; i++)
            af[i] = *(const bf16x8*)&As[(wr + i * 16 + m16) * 4 + quad];
        #pragma unroll
        for (int j = 0; j < 4; j++)
            bfr[j] = *(const bf16x8*)&Bs[(wc + j * 16 + m16) * 4 + quad];

        #pragma unroll
        for (int i = 0; i < 4; i++)
            #pragma unroll
            for (int j = 0; j < 4; j++)
                acc[i][j] = __builtin_amdgcn_mfma_f32_16x16x32_bf16(af[i], bfr[j], acc[i][j], 0, 0, 0);
    }

    #pragma unroll
    for (int i = 0; i < 4; i++)
        #pragma unroll
        for (int j = 0; j < 4; j++) {
            int col = bn + wc + j * 16 + m16;
            if (col < Npad) {
                bool real = col < N;
                float bv = real ? bias[col] : 0.f;
                #pragma unroll
                for (int r = 0; r < 4; r++) {
                    int m = bm + wr + i * 16 + quad * 4 + r;
                    float o = real ? tanhf(acc[i][j][r] + bv) : 0.f;
                    C[(size_t)m * ldc + col] = f2b(o);
                }
            }
        }
}

// ---------------------------------------------------------------------------
// Zero-workspace fallback: one block per batch row, activations in LDS.
// ---------------------------------------------------------------------------
__device__ __forceinline__ void head_dev(const bf16* a, int D, const float* lw,
                                         const float* lb, float* out, int oidx,
                                         float* red, int tid) {
    float s = 0.f;
    for (int t = tid; t < D; t += 256) s += b2f(a[t]) * lw[t];
    #pragma unroll
    for (int off = 32; off > 0; off >>= 1) s += __shfl_down(s, off);
    __syncthreads();
    if ((tid & 63) == 0) red[tid >> 6] = s;
    __syncthreads();
    if (tid == 0) {
        float t = red[0] + red[1] + red[2] + red[3] + lb[0];
        out[oidx] = 1.f / (1.f + expf(-t));
    }
}

__device__ __forceinline__ void layer_dev(const bf16* ain, int K, int N,
                                          const float* W, const int* m,
                                          const float* bias, bf16* aout, int Npad, int tid) {
    __syncthreads();
    for (int n = tid; n < Npad; n += 256) {
        float v = 0.f;
        if (n < N) {
            float s = 0.f;
            for (int k = 0; k < K; k++) {
                size_t idx = (size_t)k * N + n;
                if (m[idx]) s += b2f(ain[k]) * W[idx];
            }
            v = tanhf(s + bias[n]);
        }
        aout[n] = f2b(v);
    }
    __syncthreads();
}

__global__ __launch_bounds__(256) void forward_monolithic(
        const float* __restrict__ x, const float* __restrict__ w0, const float* __restrict__ b0,
        const float* W1, const float* bb1, const int* m1,
        const float* W2, const float* bb2, const int* m2,
        const float* W3, const float* bb3, const int* m3,
        const float* W4, const float* bb4, const int* m4,
        const float* W5, const float* bb5, const int* m5,
        const float* l1w, const float* l1b, const float* l2w, const float* l2b,
        const float* l3w, const float* l3b, const float* l4w, const float* l4b,
        const float* l5w, const float* l5b, const float* l6w, const float* l6b,
        float* __restrict__ out) {
    __shared__ bf16 A0[9232];
    __shared__ bf16 A1[1392];
    __shared__ bf16 A2[1072];
    __shared__ bf16 A3[448];
    __shared__ bf16 A4[160];
    __shared__ bf16 A5[32];
    __shared__ float red[4];
    int b = blockIdx.x, tid = threadIdx.x;
    const float* xr = x + (size_t)b * 27687;
    for (int g = tid; g < 9232; g += 256) {
        float v = 0.f;
        if (g < 9229) {
            int p = 3 * g;
            v = tanhf(xr[p] * w0[p] + xr[p+1] * w0[p+1] + xr[p+2] * w0[p+2] + b0[g]);
        }
        A0[g] = f2b(v);
    }
    __syncthreads();
    int ob = b * 6;
    head_dev(A0, 9229, l1w, l1b, out, ob + 0, red, tid);
    layer_dev(A0, 9229, 1387, W1, m1, bb1, A1, 1392, tid);
    head_dev(A1, 1387, l2w, l2b, out, ob + 1, red, tid);
    layer_dev(A1, 1387, 1066, W2, m2, bb2, A2, 1072, tid);
    head_dev(A2, 1066, l3w, l3b, out, ob + 2, red, tid);
    layer_dev(A2, 1066, 447, W3, m3, bb3, A3, 448, tid);
    head_dev(A3, 447, l4w, l4b, out, ob + 3, red, tid);
    layer_dev(A3, 447, 147, W4, m4, bb4, A4, 160, tid);
    head_dev(A4, 147, l5w, l5b, out, ob + 4, red, tid);
    layer_dev(A4, 147, 26, W5, m5, bb5, A5, 32, tid);
    head_dev(A5, 26, l6w, l6b, out, ob + 5, red, tid);
}

// ---------------------------------------------------------------------------

extern "C" void kernel_launch(void* const* d_in, const int* in_sizes, int n_in,
                              void* d_out, int out_size, void* d_ws, size_t ws_size,
                              hipStream_t stream) {
    const float* x  = (const float*)d_in[0];
    const float* w0 = (const float*)d_in[1];
    const float* b0 = (const float*)d_in[2];
    const float* W[5]  = {(const float*)d_in[3], (const float*)d_in[6], (const float*)d_in[9],
                          (const float*)d_in[12], (const float*)d_in[15]};
    const float* bb[5] = {(const float*)d_in[4], (const float*)d_in[7], (const float*)d_in[10],
                          (const float*)d_in[13], (const float*)d_in[16]};
    const int* mk[5] = {(const int*)d_in[5], (const int*)d_in[8], (const int*)d_in[11],
                        (const int*)d_in[14], (const int*)d_in[17]};
    const float* lw[6] = {(const float*)d_in[18], (const float*)d_in[20], (const float*)d_in[22],
                          (const float*)d_in[24], (const float*)d_in[26], (const float*)d_in[28]};
    const float* lb[6] = {(const float*)d_in[19], (const float*)d_in[21], (const float*)d_in[23],
                          (const float*)d_in[25], (const float*)d_in[27], (const float*)d_in[29]};
    float* out = (float*)d_out;
    char* ws = (char*)d_ws;
    dim3 b32(32, 32);

    if (ws_size >= 54288384) {
        // FULL split-K layout (54.3 MB):
        //   act0 @0 (18,939,904)  -- dead after gemm1; act1 (2,883,584) reuses @0
        //   act2 @18,939,904 (2,228,224)  act3 @21,168,128 (917,504)
        //   act4 @22,085,632 (327,680)    act5 @22,413,312 (65,536)
        //   wtR  @22,478,848 (26,042,368) -- wt1, then recycled for wt2..wt5
        //   C32  @48,521,216 (5,767,168)  -- fp32 split-K accumulator
        bf16* act0 = (bf16*)(ws + 0);
        bf16* act1 = (bf16*)(ws + 0);            // reuse after gemm1 (stream-ordered)
        bf16* act2 = (bf16*)(ws + 18939904);
        bf16* act3 = (bf16*)(ws + 21168128);
        bf16* act4 = (bf16*)(ws + 22085632);
        bf16* act5 = (bf16*)(ws + 22413312);
        bf16* wtR  = (bf16*)(ws + 22478848);
        float* C32 = (float*)(ws + 48521216);

        diag_tanh<<<dim3(37, 1024), 256, 0, stream>>>(x, w0, b0, act0);
        head_sig<<<1024, 256, 0, stream>>>(act0, 9248, 9229, lw[0], lb[0], out, 0);

        // Layer 1: K=9248 (289 iters), 11x8 tiles, S=12 (chunk 25) -> 1056 blocks
        prep_wt<<<dim3(289, 44), b32, 0, stream>>>(W[0], mk[0], wtR, 9229, 1387, 9248);
        zero_f32<<<1408, 256, 0, stream>>>(C32, 360448);
        gemm_bt_splitk<<<dim3(11, 8, 12), 256, 0, stream>>>(act0, wtR, C32, 9248, 1408, 1408, 289, 25);
        finalize_tanh<<<dim3(6, 1024), 256, 0, stream>>>(C32, bb[0], act1, 1408, 1387);
        head_sig<<<1024, 256, 0, stream>>>(act1, 1408, 1387, lw[1], lb[1], out, 1);

        // Layer 2: K=1408 (44 iters), 9x8 tiles, S=4 (chunk 11) -> 288 blocks
        prep_wt<<<dim3(44, 36), b32, 0, stream>>>(W[1], mk[1], wtR, 1387, 1066, 1408);
        zero_f32<<<1088, 256, 0, stream>>>(C32, 278528);
        gemm_bt_splitk<<<dim3(9, 8, 4), 256, 0, stream>>>(act1, wtR, C32, 1408, 1088, 1088, 44, 11);
        finalize_tanh<<<dim3(5, 1024), 256, 0, stream>>>(C32, bb[1], act2, 1088, 1066);
        head_sig<<<1024, 256, 0, stream>>>(act2, 1088, 1066, lw[2], lb[2], out, 2);

        // Layer 3: K=1088 (34 iters), 4x8 tiles, S=7 (chunk 5) -> 224 blocks
        prep_wt<<<dim3(34, 16), b32, 0, stream>>>(W[2], mk[2], wtR, 1066, 447, 1088);
        zero_f32<<<448, 256, 0, stream>>>(C32, 114688);
        gemm_bt_splitk<<<dim3(4, 8, 7), 256, 0, stream>>>(act2, wtR, C32, 1088, 448, 448, 34, 5);
        finalize_tanh<<<dim3(2, 1024), 256, 0, stream>>>(C32, bb[2], act3, 448, 447);
        head_sig<<<1024, 256, 0, stream>>>(act3, 448, 447, lw[3], lb[3], out, 3);

        // Layers 4,5: tiny; keep fused epilogue
        prep_wt<<<dim3(14, 8), b32, 0, stream>>>(W[3], mk[3], wtR, 447, 147, 448);
        gemm_bt_tanh<<<dim3(2, 8), 256, 0, stream>>>(act3, wtR, bb[3], act4, 448, 147, 160, 160, 14);
        head_sig<<<1024, 256, 0, stream>>>(act4, 160, 147, lw[4], lb[4], out, 4);
        prep_wt<<<dim3(5, 4), b32, 0, stream>>>(W[4], mk[4], wtR, 147, 26, 160);
        gemm_bt_tanh<<<dim3(1, 8), 256, 0, stream>>>(act4, wtR, bb[4], act5, 160, 26, 32, 32, 5);
        head_sig<<<1024, 256, 0, stream>>>(act5, 32, 26, lw[5], lb[5], out, 5);
    } else {
        forward_monolithic<<<1024, 256, 0, stream>>>(
            x, w0, b0,
            W[0], bb[0], mk[0], W[1], bb[1], mk[1], W[2], bb[2], mk[2],
            W[3], bb[3], mk[3], W[4], bb[4], mk[4],
            lw[0], lb[0], lw[1], lb[1], lw[2], lb[2],
            lw[3], lb[3], lw[4], lb[4], lw[5], lb[5], out);
    }
}